// Round 1
// baseline (1251.949 us; speedup 1.0000x reference)
//
#include <hip/hip_runtime.h>
#include <stdint.h>

// HashGridEncoding: tcnn hashgrid (L=16, F=2, T=2^19, base=16, scale=1.5)
// fused with Linear(32 -> 64). fp32 in/out.
//
// Phase 1: one thread per point, 16 levels x 8 float2 gathers, trilinear interp.
// Phase 2: enc staged through LDS; each wave: lane -> output channel j (j and j+32),
//          W rows in VGPRs, enc broadcast-read from LDS, fully coalesced stores.

constexpr int LVLS = 16;
constexpr uint32_t TSIZE = 1u << 19;
constexpr int RAW = 32;   // L*F
constexpr int ODIM = 64;

__device__ __forceinline__ uint32_t umin32(uint32_t a, uint32_t b) { return a < b ? a : b; }

__global__ __launch_bounds__(256) void hashgrid_fused(
    const float* __restrict__ x,
    const float* __restrict__ table,
    const float* __restrict__ W,
    const float* __restrict__ bias,
    float* __restrict__ out)
{
    // scale_l = 16*1.5^l - 1 (exactly representable in f32); res_l = ceil(scale)+1
    static constexpr float kScale[LVLS] = {
        15.0f, 23.0f, 35.0f, 53.0f, 80.0f, 120.5f, 181.25f, 272.375f,
        409.0625f, 614.09375f, 921.640625f, 1382.9609375f,
        2074.94140625f, 3112.912109375f, 4669.8681640625f, 7005.30224609375f};
    static constexpr uint32_t kRes[LVLS] = {
        16, 24, 36, 54, 81, 122, 183, 274, 411, 616, 923, 1384, 2076, 3114, 4671, 7007};
    // levels 0..3 dense (res^3 <= T), 4..15 hashed

    __shared__ float encS[256 * 36];  // 256 rows, stride 36 floats (144B, 16B-aligned)

    const int tid = threadIdx.x;
    const int p = blockIdx.x * 256 + tid;   // P is an exact multiple of 256

    float enc[RAW];

    {
        const float xr0 = x[3 * p + 0];
        const float xr1 = x[3 * p + 1];
        const float xr2 = x[3 * p + 2];
        const float xn0 = (xr0 + 1.0f) * 0.5f;
        const float xn1 = (xr1 + 1.0f) * 0.5f;
        const float xn2 = (xr2 + 1.0f) * 0.5f;

#pragma unroll
        for (int l = 0; l < LVLS; ++l) {
            const float s = kScale[l];
            const uint32_t res = kRes[l];

            const float pa = xn0 * s + 0.5f;
            const float pb = xn1 * s + 0.5f;
            const float pc = xn2 * s + 0.5f;
            const float fa = floorf(pa);
            const float fb = floorf(pb);
            const float fc = floorf(pc);
            const float ra = pa - fa;
            const float rb = pb - fb;
            const float rc = pc - fc;
            const uint32_t ca = (uint32_t)fa;
            const uint32_t cb = (uint32_t)fb;
            const uint32_t cc = (uint32_t)fc;

            uint32_t idx[8];
            if (l < 4) {
                // dense: idx = cx + cy*res + cz*res^2, coords clamped to res-1
                const uint32_t rm = res - 1u;
                const uint32_t rr = res * res;
                const uint32_t x0 = umin32(ca, rm);
                const uint32_t x1 = umin32(ca + 1u, rm);
                const uint32_t y0 = umin32(cb, rm) * res;
                const uint32_t y1 = umin32(cb + 1u, rm) * res;
                const uint32_t z0 = umin32(cc, rm) * rr;
                const uint32_t z1 = umin32(cc + 1u, rm) * rr;
                idx[0] = x0 + y0 + z0;
                idx[1] = x0 + y0 + z1;
                idx[2] = x0 + y1 + z0;
                idx[3] = x0 + y1 + z1;
                idx[4] = x1 + y0 + z0;
                idx[5] = x1 + y0 + z1;
                idx[6] = x1 + y1 + z0;
                idx[7] = x1 + y1 + z1;
            } else {
                // hashed: (cx*1) ^ (cy*2654435761) ^ (cz*805459861), mod T
                const uint32_t hx0 = ca;
                const uint32_t hx1 = ca + 1u;
                const uint32_t hy0 = cb * 2654435761u;
                const uint32_t hy1 = hy0 + 2654435761u;
                const uint32_t hz0 = cc * 805459861u;
                const uint32_t hz1 = hz0 + 805459861u;
                idx[0] = (hx0 ^ hy0 ^ hz0) & (TSIZE - 1u);
                idx[1] = (hx0 ^ hy0 ^ hz1) & (TSIZE - 1u);
                idx[2] = (hx0 ^ hy1 ^ hz0) & (TSIZE - 1u);
                idx[3] = (hx0 ^ hy1 ^ hz1) & (TSIZE - 1u);
                idx[4] = (hx1 ^ hy0 ^ hz0) & (TSIZE - 1u);
                idx[5] = (hx1 ^ hy0 ^ hz1) & (TSIZE - 1u);
                idx[6] = (hx1 ^ hy1 ^ hz0) & (TSIZE - 1u);
                idx[7] = (hx1 ^ hy1 ^ hz1) & (TSIZE - 1u);
            }

            const float2* tl = reinterpret_cast<const float2*>(table) + (size_t)l * TSIZE;
            float2 g[8];
#pragma unroll
            for (int k = 0; k < 8; ++k) g[k] = tl[idx[k]];

            const float wa0 = 1.0f - ra, wa1 = ra;
            const float wb0 = 1.0f - rb, wb1 = rb;
            const float wc0 = 1.0f - rc, wc1 = rc;
            float e0 = 0.0f, e1 = 0.0f;
#pragma unroll
            for (int k = 0; k < 8; ++k) {
                const float w = ((k & 4) ? wa1 : wa0) * ((k & 2) ? wb1 : wb0) * ((k & 1) ? wc1 : wc0);
                e0 = fmaf(w, g[k].x, e0);
                e1 = fmaf(w, g[k].y, e1);
            }
            enc[2 * l] = e0;
            enc[2 * l + 1] = e1;
        }
    }

    // stage enc -> LDS (row stride 36 floats keeps float4 alignment)
    {
        float4* encV = reinterpret_cast<float4*>(enc);
        float4* row = reinterpret_cast<float4*>(&encS[tid * 36]);
#pragma unroll
        for (int k = 0; k < 8; ++k) row[k] = encV[k];
    }

    // per-lane W rows (j0 and j0+32) into VGPRs; issued before barrier to hide latency
    const int lane = tid & 63;
    const int wv = tid >> 6;
    const int j0 = lane & 31;
    const int half = lane >> 5;

    float Wreg0[RAW], Wreg1[RAW];
    {
        const float4* W4 = reinterpret_cast<const float4*>(W);
        float4* w0 = reinterpret_cast<float4*>(Wreg0);
        float4* w1 = reinterpret_cast<float4*>(Wreg1);
#pragma unroll
        for (int k = 0; k < 8; ++k) {
            w0[k] = W4[j0 * 8 + k];
            w1[k] = W4[(j0 + 32) * 8 + k];
        }
    }
    const float b0 = bias[j0];
    const float b1 = bias[j0 + 32];

    __syncthreads();

    // phase 2: wave wv covers block-local points [wv*64, wv*64+64)
    // lane half h handles point 2i+h; lane's channels are j0 and j0+32.
    const size_t outBase = (size_t)blockIdx.x * 256 * ODIM;
#pragma unroll 2
    for (int i = 0; i < 32; ++i) {
        const int q = wv * 64 + 2 * i + half;
        const float4* er = reinterpret_cast<const float4*>(&encS[q * 36]);
        float acc0 = b0, acc1 = b1;
#pragma unroll
        for (int k4 = 0; k4 < 8; ++k4) {
            const float4 e = er[k4];
            acc0 = fmaf(e.x, Wreg0[4 * k4 + 0], acc0);
            acc1 = fmaf(e.x, Wreg1[4 * k4 + 0], acc1);
            acc0 = fmaf(e.y, Wreg0[4 * k4 + 1], acc0);
            acc1 = fmaf(e.y, Wreg1[4 * k4 + 1], acc1);
            acc0 = fmaf(e.z, Wreg0[4 * k4 + 2], acc0);
            acc1 = fmaf(e.z, Wreg1[4 * k4 + 2], acc1);
            acc0 = fmaf(e.w, Wreg0[4 * k4 + 3], acc0);
            acc1 = fmaf(e.w, Wreg1[4 * k4 + 3], acc1);
        }
        float* o = out + outBase + (size_t)q * ODIM;
        o[j0] = acc0;
        o[j0 + 32] = acc1;
    }
}

extern "C" void kernel_launch(void* const* d_in, const int* in_sizes, int n_in,
                              void* d_out, int out_size, void* d_ws, size_t ws_size,
                              hipStream_t stream) {
    const float* x = (const float*)d_in[0];      // [B,N,3]
    const float* table = (const float*)d_in[1];  // [L,T,F]
    const float* W = (const float*)d_in[2];      // [64,32]
    const float* b = (const float*)d_in[3];      // [64]
    float* out = (float*)d_out;                  // [B,N,64]

    const int P = in_sizes[0] / 3;               // 1048576, multiple of 256
    const int blocks = P / 256;
    hipLaunchKernelGGL(hashgrid_fused, dim3(blocks), dim3(256), 0, stream,
                       x, table, W, b, out);
}